// Round 17
// baseline (55.424 us; speedup 1.0000x reference)
//
#include <hip/hip_runtime.h>

typedef __attribute__((ext_vector_type(8)))  __bf16 bf16x8;
typedef __attribute__((ext_vector_type(16))) float  f32x16;

#define DEV __device__ __forceinline__

namespace {

constexpr int BB = 32, CC = 3, TT = 2048, KK = 128, OUTK = 384;
constexpr int TP = 2176;   // padded x-copy row length (elements)

// ---- workspace byte offsets ----
constexpr size_t OFF_B16 = 0;                       // B-frags S16
constexpr size_t OFF_B32 = 12288;
constexpr size_t OFF_B64 = 36864;
constexpr size_t OFF_S2  = 86016;                   // [3][CC][KK] f32
constexpr size_t OFF_X2  = 90624;                   // [3][BB][CC][TT] f32
constexpr size_t OFF_XC  = 2449920;                 // [BB][CC][8][TP] bf16 (ends 5792256)
constexpr size_t OFF_PRB = 5832704;                 // probe scratch (49 KB)

DEV unsigned short rne(float f) {
  unsigned u = __float_as_uint(f);
  u += 0x7FFFu + ((u >> 16) & 1u);
  return (unsigned short)(u >> 16);
}
DEV float rnef(float f) {
  unsigned u = __float_as_uint(f);
  u += 0x7FFFu + ((u >> 16) & 1u);
  return __uint_as_float(u & 0xFFFF0000u);
}
DEV uint4 pack8(const unsigned short* h) {
  uint4 d;
  d.x = (unsigned)h[0] | ((unsigned)h[1] << 16);
  d.y = (unsigned)h[2] | ((unsigned)h[3] << 16);
  d.z = (unsigned)h[4] | ((unsigned)h[5] << 16);
  d.w = (unsigned)h[6] | ((unsigned)h[7] << 16);
  return d;
}
DEV float f4get(const float4 v, int j) {
  switch (j) { case 0: return v.x; case 1: return v.y; case 2: return v.z; default: return v.w; }
}

// ---------------- precompute (identical to rounds 4-16, verified) ----------------
constexpr int N_OUT = BB * OUTK;
constexpr int N_BF  = 5376;
constexpr int N_S2  = 1152;
constexpr int N_XC  = BB * CC * 8 * (TP/8);
constexpr int N_X2  = BB * CC * TT;
constexpr int N_TOT = N_OUT + N_BF + N_S2 + N_XC + N_X2;

__global__ __launch_bounds__(256) void precompute(
    const float* __restrict__ x, const float* __restrict__ sh16,
    const float* __restrict__ sh32, const float* __restrict__ sh64,
    unsigned char* __restrict__ ws, unsigned* __restrict__ outu)
{
  int i = blockIdx.x * 256 + threadIdx.x;
  if (i >= N_TOT) return;
  if (i < N_OUT) { outu[i] = 0x7f800000u; return; }
  i -= N_OUT;

  if (i < N_BF) {
    int S, it; const float* sh; size_t boff;
    if (i < 768)       { S = 16; it = i;        sh = sh16; boff = OFF_B16; }
    else if (i < 2304) { S = 32; it = i - 768;  sh = sh32; boff = OFF_B32; }
    else               { S = 64; it = i - 2304; sh = sh64; boff = OFF_B64; }
    const int CHS = S / 8, KST = S / 16;
    int c = it / (KK * CHS); int r = it - c * KK * CHS;
    int n = r / CHS;         int k0 = (r - n * CHS) * 8;
    const float* src = sh + ((size_t)(c * KK + n)) * S + k0;
    unsigned short h[8];
    #pragma unroll
    for (int j = 0; j < 8; ++j) h[j] = rne(src[j]);
    ((uint4*)(ws + boff))[((c * 4 + (n >> 5)) * KST + (k0 >> 4)) * 64 + ((k0 >> 3) & 1) * 32 + (n & 31)] = pack8(h);
    return;
  }
  i -= N_BF;

  if (i < N_S2) {
    int Sidx = i / 384; int r = i - Sidx * 384; int c = r >> 7; int k = r & 127;
    int S = 16 << Sidx;
    const float* sh = (Sidx == 0) ? sh16 : ((Sidx == 1) ? sh32 : sh64);
    const float* sp = sh + ((size_t)(c * KK + k)) * S;
    float acc = 0.f;
    #pragma unroll 4
    for (int s = 0; s < S; ++s) { float v = rnef(sp[s]); acc = fmaf(v, v, acc); }
    ((float*)(ws + OFF_S2))[(Sidx * CC + c) * KK + k] = acc;
    return;
  }
  i -= N_S2;

  if (i < N_XC) {
    const int per = TP / 8;
    int c8 = i / per; int q8 = i - c8 * per;
    int p  = c8 & 7;  int bc = c8 >> 3;
    const float* xb = x + (size_t)bc * TT;
    int m0 = q8 * 8;
    unsigned short h[8];
    #pragma unroll
    for (int j = 0; j < 8; ++j) {
      int mi = m0 + j + p;
      float v = (mi < TT) ? xb[mi] : 0.f;
      h[j] = rne(v);
    }
    ((uint4*)(ws + OFF_XC + (size_t)c8 * TP * 2))[q8] = pack8(h);
    return;
  }
  i -= N_XC;

  {
    int w = i & (TT - 1); int bc = i >> 11;
    const float* xb = x + (size_t)bc * TT;
    float acc = 0.f, a16, a32, a64;
    #pragma unroll 4
    for (int s = 0; s < 16; ++s) { int mi = w + s; float v = (mi < TT) ? rnef(xb[mi]) : 0.f; acc = fmaf(v, v, acc); }
    a16 = acc;
    #pragma unroll 4
    for (int s = 16; s < 32; ++s) { int mi = w + s; float v = (mi < TT) ? rnef(xb[mi]) : 0.f; acc = fmaf(v, v, acc); }
    a32 = acc;
    #pragma unroll 4
    for (int s = 32; s < 64; ++s) { int mi = w + s; float v = (mi < TT) ? rnef(xb[mi]) : 0.f; acc = fmaf(v, v, acc); }
    a64 = acc;
    float* x2 = (float*)(ws + OFF_X2);
    x2[(size_t)(0 * BB * CC + bc) * TT + w] = a16;
    x2[(size_t)(1 * BB * CC + bc) * TT + w] = a32;
    x2[(size_t)(2 * BB * CC + bc) * TT + w] = a64;
  }
}

// -------- main: r16 body, byte-identical (best-known 39.5 baseline) --------
DEV void epi(const f32x16 a, const float* __restrict__ x2c, float s2c, int lhi, f32x16& dsum) {
  #pragma unroll
  for (int g = 0; g < 4; ++g) {
    const float4 xq = *(const float4*)(x2c + 4 * lhi + 8 * g);   // LDS broadcast, aligned
    #pragma unroll
    for (int j = 0; j < 4; ++j) {
      const int r2 = g * 4 + j;
      dsum[r2] += __builtin_amdgcn_sqrtf(fmaxf(fmaf(-2.f, a[r2], f4get(xq, j) + s2c), 1e-12f));
    }
  }
}

template<int S, int KST, int OUTOFF, size_t BOFF, int SIDX>
DEV void run(const unsigned char* __restrict__ ws, unsigned* __restrict__ outu,
             int r, float* __restrict__ x2l, float* __restrict__ s2l,
             float* __restrict__ mred)
{
  const int b = r >> 4, wg = r & 15;          // 16 w-groups of 128
  const int tid = (int)threadIdx.x;
  const int lane = tid & 63, wsub = tid >> 6;
  const int l31 = lane & 31, lhi = lane >> 5, p = l31 & 7;
  const int w0 = wg * 128 + wsub * 32;

  const uint4* Bg = (const uint4*)(ws + BOFF) + lane;

  uint4 Bb[2][KST];
  #pragma unroll
  for (int kk = 0; kk < KST; ++kk) Bb[0][kk] = Bg[(size_t)kk * 64];

  const unsigned short* XCb = (const unsigned short*)(ws + OFF_XC);
  uint4 A[CC][KST];
  #pragma unroll
  for (int c = 0; c < CC; ++c) {
    const unsigned short* xA = XCb + ((size_t)((b * CC + c) * 8) + p) * TP
                             + (w0 + 8 * (l31 >> 3) + 8 * lhi);
    #pragma unroll
    for (int kk = 0; kk < KST; ++kk) A[c][kk] = *(const uint4*)(xA + 16 * kk);
  }

  const float* x2g = (const float*)(ws + OFF_X2) + (size_t)(SIDX * BB * CC + b * CC) * TT + wg * 128;
  const float* s2g = (const float*)(ws + OFF_S2) + SIDX * CC * KK;
  #pragma unroll
  for (int i0 = 0; i0 < 2; ++i0) {
    int i = i0 * 256 + tid;
    if (i < 384) {
      int c = i >> 7, q = i & 127;
      x2l[i] = x2g[(size_t)c * TT + q];
      s2l[i] = s2g[c * KK + q];
    }
  }
  __syncthreads();

  constexpr int W = TT - S + 1;
  float mq[4];

  #pragma unroll
  for (int kq = 0; kq < 4; ++kq) {
    f32x16 dsum{};
    #pragma unroll
    for (int c = 0; c < CC; ++c) {
      const int g  = kq * CC + c;
      const int pb = g & 1;
      if (g < 4 * CC - 1) {
        const int ng = g + 1;
        const int nkq = ng / CC, nc = ng - nkq * CC;
        #pragma unroll
        for (int kk = 0; kk < KST; ++kk)
          Bb[pb ^ 1][kk] = Bg[(size_t)(((nc * 4 + nkq) * KST + kk)) * 64];
      }
      f32x16 acc{};
      #pragma unroll
      for (int kk = 0; kk < KST; ++kk)
        acc = __builtin_amdgcn_mfma_f32_32x32x16_bf16(
            __builtin_bit_cast(bf16x8, A[c][kk]), __builtin_bit_cast(bf16x8, Bb[pb][kk]), acc, 0, 0, 0);
      const float s2c = s2l[c * 128 + kq * 32 + l31];
      epi(acc, x2l + c * 128 + wsub * 32, s2c, lhi, dsum);
    }
    float m = __builtin_inff();
    if (w0 + 31 < W) {
      #pragma unroll
      for (int r2 = 0; r2 < 16; ++r2) m = fminf(m, dsum[r2]);
    } else {
      #pragma unroll
      for (int r2 = 0; r2 < 16; ++r2) {
        const int ro = (r2 & 3) + 8 * (r2 >> 2) + 4 * lhi;
        if (w0 + ro < W) m = fminf(m, dsum[r2]);
      }
    }
    mq[kq] = fminf(m, __shfl_xor(m, 32));
  }

  if (lane < 32) {
    #pragma unroll
    for (int kq = 0; kq < 4; ++kq) mred[(wsub * 4 + kq) * 32 + l31] = mq[kq];
  }
  __syncthreads();
  if (tid < 128) {
    const int kq = tid >> 5, q = tid & 31;
    float v = fminf(fminf(mred[(0 * 4 + kq) * 32 + q], mred[(1 * 4 + kq) * 32 + q]),
                    fminf(mred[(2 * 4 + kq) * 32 + q], mred[(3 * 4 + kq) * 32 + q]));
    atomicMin(outu + (b * OUTK + OUTOFF + kq * 32 + q), __float_as_uint(v));
  }
}

__global__ __launch_bounds__(256, 3) void shapelets_main(
    const unsigned char* __restrict__ ws, unsigned* __restrict__ outu)
{
  __shared__ __attribute__((aligned(16))) float x2l[384];
  __shared__ __attribute__((aligned(16))) float s2l[384];
  __shared__ __attribute__((aligned(16))) float mred[512];
  const int j    = (int)blockIdx.x;
  const int bl   = j & 7;
  const int midx = j >> 3;
  const int wg   = midx & 15;
  const int bh   = (midx >> 4) & 3;
  const int So   = midx >> 6;
  const int r    = (bh * 8 + bl) * 16 + wg;
  if (So == 0)      run<64, 4, 256, OFF_B64, 2>(ws, outu, r, x2l, s2l, mred);
  else if (So == 1) run<32, 2, 128, OFF_B32, 1>(ws, outu, r, x2l, s2l, mred);
  else              run<16, 1,   0, OFF_B16, 0>(ws, outu, r, x2l, s2l, mred);
}

// -------- ABLATION PROBE: identical skeleton (stage, A-hoist, B-dbuf, MFMA),
//          epilogue reduced to 1 fma/element; atomics -> ws scratch.
//          probe_cost = dur_us - 39.5 localizes the 24 us stall. --------
template<int S, int KST, int OUTOFF, size_t BOFF, int SIDX>
DEV void run_probe(const unsigned char* __restrict__ ws, unsigned* __restrict__ prb,
                   int r, float* __restrict__ x2l, float* __restrict__ s2l)
{
  const int b = r >> 4, wg = r & 15;
  const int tid = (int)threadIdx.x;
  const int lane = tid & 63, wsub = tid >> 6;
  const int l31 = lane & 31, lhi = lane >> 5, p = l31 & 7;
  const int w0 = wg * 128 + wsub * 32;

  const uint4* Bg = (const uint4*)(ws + BOFF) + lane;
  uint4 Bb[2][KST];
  #pragma unroll
  for (int kk = 0; kk < KST; ++kk) Bb[0][kk] = Bg[(size_t)kk * 64];

  const unsigned short* XCb = (const unsigned short*)(ws + OFF_XC);
  uint4 A[CC][KST];
  #pragma unroll
  for (int c = 0; c < CC; ++c) {
    const unsigned short* xA = XCb + ((size_t)((b * CC + c) * 8) + p) * TP
                             + (w0 + 8 * (l31 >> 3) + 8 * lhi);
    #pragma unroll
    for (int kk = 0; kk < KST; ++kk) A[c][kk] = *(const uint4*)(xA + 16 * kk);
  }

  const float* x2g = (const float*)(ws + OFF_X2) + (size_t)(SIDX * BB * CC + b * CC) * TT + wg * 128;
  const float* s2g = (const float*)(ws + OFF_S2) + SIDX * CC * KK;
  #pragma unroll
  for (int i0 = 0; i0 < 2; ++i0) {
    int i = i0 * 256 + tid;
    if (i < 384) {
      int c = i >> 7, q = i & 127;
      x2l[i] = x2g[(size_t)c * TT + q];
      s2l[i] = s2g[c * KK + q];
    }
  }
  __syncthreads();

  float mq[4];
  #pragma unroll
  for (int kq = 0; kq < 4; ++kq) {
    f32x16 dsum{};
    #pragma unroll
    for (int c = 0; c < CC; ++c) {
      const int g  = kq * CC + c;
      const int pb = g & 1;
      if (g < 4 * CC - 1) {
        const int ng = g + 1;
        const int nkq = ng / CC, nc = ng - nkq * CC;
        #pragma unroll
        for (int kk = 0; kk < KST; ++kk)
          Bb[pb ^ 1][kk] = Bg[(size_t)(((nc * 4 + nkq) * KST + kk)) * 64];
      }
      f32x16 acc{};
      #pragma unroll
      for (int kk = 0; kk < KST; ++kk)
        acc = __builtin_amdgcn_mfma_f32_32x32x16_bf16(
            __builtin_bit_cast(bf16x8, A[c][kk]), __builtin_bit_cast(bf16x8, Bb[pb][kk]), acc, 0, 0, 0);
      const float s2c = s2l[c * 128 + kq * 32 + l31];
      #pragma unroll
      for (int r2 = 0; r2 < 16; ++r2)
        dsum[r2] = fmaf(acc[r2], s2c, dsum[r2]);   // skeleton consume: no sqrt/max/x2
    }
    float m = __builtin_inff();
    #pragma unroll
    for (int r2 = 0; r2 < 16; ++r2) m = fminf(m, dsum[r2]);
    mq[kq] = fminf(m, __shfl_xor(m, 32));
  }
  if (lane < 32) {
    #pragma unroll
    for (int kq = 0; kq < 4; ++kq)
      atomicMin(prb + (b * OUTK + OUTOFF + kq * 32 + l31), __float_as_uint(mq[kq]));
  }
}

__global__ __launch_bounds__(256, 3) void shapelets_probe(
    const unsigned char* __restrict__ ws, unsigned* __restrict__ prb)
{
  __shared__ __attribute__((aligned(16))) float x2l[384];
  __shared__ __attribute__((aligned(16))) float s2l[384];
  const int j    = (int)blockIdx.x;
  const int bl   = j & 7;
  const int midx = j >> 3;
  const int wg   = midx & 15;
  const int bh   = (midx >> 4) & 3;
  const int So   = midx >> 6;
  const int r    = (bh * 8 + bl) * 16 + wg;
  if (So == 0)      run_probe<64, 4, 256, OFF_B64, 2>(ws, prb, r, x2l, s2l);
  else if (So == 1) run_probe<32, 2, 128, OFF_B32, 1>(ws, prb, r, x2l, s2l);
  else              run_probe<16, 1,   0, OFF_B16, 0>(ws, prb, r, x2l, s2l);
}

} // namespace

extern "C" void kernel_launch(void* const* d_in, const int* in_sizes, int n_in,
                              void* d_out, int out_size, void* d_ws, size_t ws_size,
                              hipStream_t stream) {
  const float* x    = (const float*)d_in[0];
  const float* sh16 = (const float*)d_in[1];
  const float* sh32 = (const float*)d_in[2];
  const float* sh64 = (const float*)d_in[3];
  unsigned* outu = (unsigned*)d_out;
  unsigned char* ws = (unsigned char*)d_ws;

  precompute<<<(N_TOT + 255) / 256, 256, 0, stream>>>(x, sh16, sh32, sh64, ws, outu);
  shapelets_main<<<1536, 256, 0, stream>>>(ws, outu);
  if (ws_size >= OFF_PRB + (size_t)BB * OUTK * 4)    // ablation probe (output-neutral)
    shapelets_probe<<<1536, 256, 0, stream>>>(ws, (unsigned*)(ws + OFF_PRB));
}

// Round 18
// 40.420 us; speedup vs baseline: 1.3712x; 1.3712x over previous
//
#include <hip/hip_runtime.h>

typedef __attribute__((ext_vector_type(8)))  __bf16 bf16x8;
typedef __attribute__((ext_vector_type(16))) float  f32x16;

#define DEV __device__ __forceinline__

namespace {

constexpr int BB = 32, CC = 3, TT = 2048, KK = 128, OUTK = 384;
constexpr int TP = 2176;   // padded x-copy row length (elements)

// ---- workspace byte offsets ----
constexpr size_t OFF_B16 = 0;                       // B-frags S16
constexpr size_t OFF_B32 = 12288;
constexpr size_t OFF_B64 = 36864;
constexpr size_t OFF_S2  = 86016;                   // [3][CC][KK] f32
constexpr size_t OFF_X2  = 90624;                   // [3][BB][CC][TT] f32
constexpr size_t OFF_XC  = 2449920;                 // [BB][CC][8][TP] bf16

DEV unsigned short rne(float f) {
  unsigned u = __float_as_uint(f);
  u += 0x7FFFu + ((u >> 16) & 1u);
  return (unsigned short)(u >> 16);
}
DEV float rnef(float f) {
  unsigned u = __float_as_uint(f);
  u += 0x7FFFu + ((u >> 16) & 1u);
  return __uint_as_float(u & 0xFFFF0000u);
}
DEV uint4 pack8(const unsigned short* h) {
  uint4 d;
  d.x = (unsigned)h[0] | ((unsigned)h[1] << 16);
  d.y = (unsigned)h[2] | ((unsigned)h[3] << 16);
  d.z = (unsigned)h[4] | ((unsigned)h[5] << 16);
  d.w = (unsigned)h[6] | ((unsigned)h[7] << 16);
  return d;
}
DEV float f4get(const float4 v, int j) {
  switch (j) { case 0: return v.x; case 1: return v.y; case 2: return v.z; default: return v.w; }
}

// ---------------- precompute (identical to rounds 4-17, verified) ----------------
constexpr int N_OUT = BB * OUTK;
constexpr int N_BF  = 5376;
constexpr int N_S2  = 1152;
constexpr int N_XC  = BB * CC * 8 * (TP/8);
constexpr int N_X2  = BB * CC * TT;
constexpr int N_TOT = N_OUT + N_BF + N_S2 + N_XC + N_X2;

__global__ __launch_bounds__(256) void precompute(
    const float* __restrict__ x, const float* __restrict__ sh16,
    const float* __restrict__ sh32, const float* __restrict__ sh64,
    unsigned char* __restrict__ ws, unsigned* __restrict__ outu)
{
  int i = blockIdx.x * 256 + threadIdx.x;
  if (i >= N_TOT) return;
  if (i < N_OUT) { outu[i] = 0x7f800000u; return; }
  i -= N_OUT;

  if (i < N_BF) {
    int S, it; const float* sh; size_t boff;
    if (i < 768)       { S = 16; it = i;        sh = sh16; boff = OFF_B16; }
    else if (i < 2304) { S = 32; it = i - 768;  sh = sh32; boff = OFF_B32; }
    else               { S = 64; it = i - 2304; sh = sh64; boff = OFF_B64; }
    const int CHS = S / 8, KST = S / 16;
    int c = it / (KK * CHS); int r = it - c * KK * CHS;
    int n = r / CHS;         int k0 = (r - n * CHS) * 8;
    const float* src = sh + ((size_t)(c * KK + n)) * S + k0;
    unsigned short h[8];
    #pragma unroll
    for (int j = 0; j < 8; ++j) h[j] = rne(src[j]);
    ((uint4*)(ws + boff))[((c * 4 + (n >> 5)) * KST + (k0 >> 4)) * 64 + ((k0 >> 3) & 1) * 32 + (n & 31)] = pack8(h);
    return;
  }
  i -= N_BF;

  if (i < N_S2) {
    int Sidx = i / 384; int r = i - Sidx * 384; int c = r >> 7; int k = r & 127;
    int S = 16 << Sidx;
    const float* sh = (Sidx == 0) ? sh16 : ((Sidx == 1) ? sh32 : sh64);
    const float* sp = sh + ((size_t)(c * KK + k)) * S;
    float acc = 0.f;
    #pragma unroll 4
    for (int s = 0; s < S; ++s) { float v = rnef(sp[s]); acc = fmaf(v, v, acc); }
    ((float*)(ws + OFF_S2))[(Sidx * CC + c) * KK + k] = acc;
    return;
  }
  i -= N_S2;

  if (i < N_XC) {
    const int per = TP / 8;
    int c8 = i / per; int q8 = i - c8 * per;
    int p  = c8 & 7;  int bc = c8 >> 3;
    const float* xb = x + (size_t)bc * TT;
    int m0 = q8 * 8;
    unsigned short h[8];
    #pragma unroll
    for (int j = 0; j < 8; ++j) {
      int mi = m0 + j + p;
      float v = (mi < TT) ? xb[mi] : 0.f;
      h[j] = rne(v);
    }
    ((uint4*)(ws + OFF_XC + (size_t)c8 * TP * 2))[q8] = pack8(h);
    return;
  }
  i -= N_XC;

  {
    int w = i & (TT - 1); int bc = i >> 11;
    const float* xb = x + (size_t)bc * TT;
    float acc = 0.f, a16, a32, a64;
    #pragma unroll 4
    for (int s = 0; s < 16; ++s) { int mi = w + s; float v = (mi < TT) ? rnef(xb[mi]) : 0.f; acc = fmaf(v, v, acc); }
    a16 = acc;
    #pragma unroll 4
    for (int s = 16; s < 32; ++s) { int mi = w + s; float v = (mi < TT) ? rnef(xb[mi]) : 0.f; acc = fmaf(v, v, acc); }
    a32 = acc;
    #pragma unroll 4
    for (int s = 32; s < 64; ++s) { int mi = w + s; float v = (mi < TT) ? rnef(xb[mi]) : 0.f; acc = fmaf(v, v, acc); }
    a64 = acc;
    float* x2 = (float*)(ws + OFF_X2);
    x2[(size_t)(0 * BB * CC + bc) * TT + w] = a16;
    x2[(size_t)(1 * BB * CC + bc) * TT + w] = a32;
    x2[(size_t)(2 * BB * CC + bc) * TT + w] = a64;
  }
}

// -- main: r16 body, single B buffer (dbuf was neutral), VGPR budget = 128 --
DEV void epi(const f32x16 a, const float* __restrict__ x2c, float s2c, int lhi, f32x16& dsum) {
  #pragma unroll
  for (int g = 0; g < 4; ++g) {
    const float4 xq = *(const float4*)(x2c + 4 * lhi + 8 * g);   // LDS broadcast, aligned
    #pragma unroll
    for (int j = 0; j < 4; ++j) {
      const int r2 = g * 4 + j;
      dsum[r2] += __builtin_amdgcn_sqrtf(fmaxf(fmaf(-2.f, a[r2], f4get(xq, j) + s2c), 1e-12f));
    }
  }
}

template<int S, int KST, int OUTOFF, size_t BOFF, int SIDX>
DEV void run(const unsigned char* __restrict__ ws, unsigned* __restrict__ outu,
             int r, float* __restrict__ x2l, float* __restrict__ s2l,
             float* __restrict__ mred)
{
  const int b = r >> 4, wg = r & 15;          // 16 w-groups of 128
  const int tid = (int)threadIdx.x;
  const int lane = tid & 63, wsub = tid >> 6;
  const int l31 = lane & 31, lhi = lane >> 5, p = l31 & 7;
  const int w0 = wg * 128 + wsub * 32;

  // ---- hoist A-fragments (verified layout): reused across all 4 kq ----
  const unsigned short* XCb = (const unsigned short*)(ws + OFF_XC);
  uint4 A[CC][KST];
  #pragma unroll
  for (int c = 0; c < CC; ++c) {
    const unsigned short* xA = XCb + ((size_t)((b * CC + c) * 8) + p) * TP
                             + (w0 + 8 * (l31 >> 3) + 8 * lhi);
    #pragma unroll
    for (int kk = 0; kk < KST; ++kk) A[c][kk] = *(const uint4*)(xA + 16 * kk);
  }

  // ---- block stage: x2[3][128] (this w-group) + s2[3][128] (full K) ----
  const float* x2g = (const float*)(ws + OFF_X2) + (size_t)(SIDX * BB * CC + b * CC) * TT + wg * 128;
  const float* s2g = (const float*)(ws + OFF_S2) + SIDX * CC * KK;
  #pragma unroll
  for (int i0 = 0; i0 < 2; ++i0) {
    int i = i0 * 256 + tid;
    if (i < 384) {
      int c = i >> 7, q = i & 127;
      x2l[i] = x2g[(size_t)c * TT + q];
      s2l[i] = s2g[c * KK + q];
    }
  }
  __syncthreads();

  const uint4* Bg = (const uint4*)(ws + BOFF) + lane;
  constexpr int W = TT - S + 1;
  float mq[4];

  #pragma unroll                              // FULL unroll (r8-proven)
  for (int kq = 0; kq < 4; ++kq) {
    f32x16 dsum{};
    #pragma unroll
    for (int c = 0; c < CC; ++c) {
      uint4 Bf[KST];
      #pragma unroll
      for (int kk = 0; kk < KST; ++kk)
        Bf[kk] = Bg[(size_t)(((c * 4 + kq) * KST + kk)) * 64];
      f32x16 acc{};
      #pragma unroll
      for (int kk = 0; kk < KST; ++kk)
        acc = __builtin_amdgcn_mfma_f32_32x32x16_bf16(
            __builtin_bit_cast(bf16x8, A[c][kk]), __builtin_bit_cast(bf16x8, Bf[kk]), acc, 0, 0, 0);
      const float s2c = s2l[c * 128 + kq * 32 + l31];
      epi(acc, x2l + c * 128 + wsub * 32, s2c, lhi, dsum);
    }
    // ---- per-kq min over rows + cross-half ----
    float m = __builtin_inff();
    if (w0 + 31 < W) {                        // wave-uniform fast path
      #pragma unroll
      for (int r2 = 0; r2 < 16; ++r2) m = fminf(m, dsum[r2]);
    } else {
      #pragma unroll
      for (int r2 = 0; r2 < 16; ++r2) {
        const int ro = (r2 & 3) + 8 * (r2 >> 2) + 4 * lhi;
        if (w0 + ro < W) m = fminf(m, dsum[r2]);
      }
    }
    mq[kq] = fminf(m, __shfl_xor(m, 32));
  }

  // ---- cross-wave LDS combine: 128 atomics/block instead of 512 ----
  if (lane < 32) {
    #pragma unroll
    for (int kq = 0; kq < 4; ++kq) mred[(wsub * 4 + kq) * 32 + l31] = mq[kq];
  }
  __syncthreads();
  if (tid < 128) {
    const int kq = tid >> 5, q = tid & 31;
    float v = fminf(fminf(mred[(0 * 4 + kq) * 32 + q], mred[(1 * 4 + kq) * 32 + q]),
                    fminf(mred[(2 * 4 + kq) * 32 + q], mred[(3 * 4 + kq) * 32 + q]));
    atomicMin(outu + (b * OUTK + OUTOFF + kq * 32 + q), __float_as_uint(v));
  }
}

// Direct VGPR budget: 128 regs -> 4 waves/SIMD (2x TLP vs the ~160-reg build).
// (launch_bounds min-waves path collapsed to 64+spill in r11/r13 — bypassed here.)
__global__ __launch_bounds__(256) __attribute__((amdgpu_num_vgpr(128)))
void shapelets_main(const unsigned char* __restrict__ ws, unsigned* __restrict__ outu)
{
  __shared__ __attribute__((aligned(16))) float x2l[384];
  __shared__ __attribute__((aligned(16))) float s2l[384];
  __shared__ __attribute__((aligned(16))) float mred[512];
  const int j    = (int)blockIdx.x;
  const int bl   = j & 7;
  const int midx = j >> 3;
  const int wg   = midx & 15;
  const int bh   = (midx >> 4) & 3;
  const int So   = midx >> 6;      // 0=S64 (first), 1=S32, 2=S16
  const int r    = (bh * 8 + bl) * 16 + wg;
  if (So == 0)      run<64, 4, 256, OFF_B64, 2>(ws, outu, r, x2l, s2l, mred);
  else if (So == 1) run<32, 2, 128, OFF_B32, 1>(ws, outu, r, x2l, s2l, mred);
  else              run<16, 1,   0, OFF_B16, 0>(ws, outu, r, x2l, s2l, mred);
}

} // namespace

extern "C" void kernel_launch(void* const* d_in, const int* in_sizes, int n_in,
                              void* d_out, int out_size, void* d_ws, size_t ws_size,
                              hipStream_t stream) {
  const float* x    = (const float*)d_in[0];
  const float* sh16 = (const float*)d_in[1];
  const float* sh32 = (const float*)d_in[2];
  const float* sh64 = (const float*)d_in[3];
  unsigned* outu = (unsigned*)d_out;
  unsigned char* ws = (unsigned char*)d_ws;

  precompute<<<(N_TOT + 255) / 256, 256, 0, stream>>>(x, sh16, sh32, sh64, ws, outu);
  shapelets_main<<<1536, 256, 0, stream>>>(ws, outu);
}

// Round 19
// 39.329 us; speedup vs baseline: 1.4092x; 1.0277x over previous
//
#include <hip/hip_runtime.h>

typedef __attribute__((ext_vector_type(8)))  __bf16 bf16x8;
typedef __attribute__((ext_vector_type(16))) float  f32x16;

#define DEV __device__ __forceinline__

namespace {

constexpr int BB = 32, CC = 3, TT = 2048, KK = 128, OUTK = 384;
constexpr int TP = 2176;   // padded x-copy row length (elements)

// ---- workspace byte offsets ----
constexpr size_t OFF_B16 = 0;                       // B-frags S16
constexpr size_t OFF_B32 = 12288;
constexpr size_t OFF_B64 = 36864;
constexpr size_t OFF_S2  = 86016;                   // [3][CC][KK] f32
constexpr size_t OFF_X2  = 90624;                   // [3][BB][CC][TT] f32
constexpr size_t OFF_XC  = 2449920;                 // [BB][CC][8][TP] bf16

DEV unsigned short rne(float f) {
  unsigned u = __float_as_uint(f);
  u += 0x7FFFu + ((u >> 16) & 1u);
  return (unsigned short)(u >> 16);
}
DEV float rnef(float f) {
  unsigned u = __float_as_uint(f);
  u += 0x7FFFu + ((u >> 16) & 1u);
  return __uint_as_float(u & 0xFFFF0000u);
}
DEV uint4 pack8(const unsigned short* h) {
  uint4 d;
  d.x = (unsigned)h[0] | ((unsigned)h[1] << 16);
  d.y = (unsigned)h[2] | ((unsigned)h[3] << 16);
  d.z = (unsigned)h[4] | ((unsigned)h[5] << 16);
  d.w = (unsigned)h[6] | ((unsigned)h[7] << 16);
  return d;
}
DEV float f4get(const float4 v, int j) {
  switch (j) { case 0: return v.x; case 1: return v.y; case 2: return v.z; default: return v.w; }
}

// ---------------- precompute (identical to rounds 4-18, verified) ----------------
constexpr int N_OUT = BB * OUTK;
constexpr int N_BF  = 5376;
constexpr int N_S2  = 1152;
constexpr int N_XC  = BB * CC * 8 * (TP/8);
constexpr int N_X2  = BB * CC * TT;
constexpr int N_TOT = N_OUT + N_BF + N_S2 + N_XC + N_X2;

__global__ __launch_bounds__(256) void precompute(
    const float* __restrict__ x, const float* __restrict__ sh16,
    const float* __restrict__ sh32, const float* __restrict__ sh64,
    unsigned char* __restrict__ ws, unsigned* __restrict__ outu)
{
  int i = blockIdx.x * 256 + threadIdx.x;
  if (i >= N_TOT) return;
  if (i < N_OUT) { outu[i] = 0x7f800000u; return; }
  i -= N_OUT;

  if (i < N_BF) {
    int S, it; const float* sh; size_t boff;
    if (i < 768)       { S = 16; it = i;        sh = sh16; boff = OFF_B16; }
    else if (i < 2304) { S = 32; it = i - 768;  sh = sh32; boff = OFF_B32; }
    else               { S = 64; it = i - 2304; sh = sh64; boff = OFF_B64; }
    const int CHS = S / 8, KST = S / 16;
    int c = it / (KK * CHS); int r = it - c * KK * CHS;
    int n = r / CHS;         int k0 = (r - n * CHS) * 8;
    const float* src = sh + ((size_t)(c * KK + n)) * S + k0;
    unsigned short h[8];
    #pragma unroll
    for (int j = 0; j < 8; ++j) h[j] = rne(src[j]);
    ((uint4*)(ws + boff))[((c * 4 + (n >> 5)) * KST + (k0 >> 4)) * 64 + ((k0 >> 3) & 1) * 32 + (n & 31)] = pack8(h);
    return;
  }
  i -= N_BF;

  if (i < N_S2) {
    int Sidx = i / 384; int r = i - Sidx * 384; int c = r >> 7; int k = r & 127;
    int S = 16 << Sidx;
    const float* sh = (Sidx == 0) ? sh16 : ((Sidx == 1) ? sh32 : sh64);
    const float* sp = sh + ((size_t)(c * KK + k)) * S;
    float acc = 0.f;
    #pragma unroll 4
    for (int s = 0; s < S; ++s) { float v = rnef(sp[s]); acc = fmaf(v, v, acc); }
    ((float*)(ws + OFF_S2))[(Sidx * CC + c) * KK + k] = acc;
    return;
  }
  i -= N_S2;

  if (i < N_XC) {
    const int per = TP / 8;
    int c8 = i / per; int q8 = i - c8 * per;
    int p  = c8 & 7;  int bc = c8 >> 3;
    const float* xb = x + (size_t)bc * TT;
    int m0 = q8 * 8;
    unsigned short h[8];
    #pragma unroll
    for (int j = 0; j < 8; ++j) {
      int mi = m0 + j + p;
      float v = (mi < TT) ? xb[mi] : 0.f;
      h[j] = rne(v);
    }
    ((uint4*)(ws + OFF_XC + (size_t)c8 * TP * 2))[q8] = pack8(h);
    return;
  }
  i -= N_XC;

  {
    int w = i & (TT - 1); int bc = i >> 11;
    const float* xb = x + (size_t)bc * TT;
    float acc = 0.f, a16, a32, a64;
    #pragma unroll 4
    for (int s = 0; s < 16; ++s) { int mi = w + s; float v = (mi < TT) ? rnef(xb[mi]) : 0.f; acc = fmaf(v, v, acc); }
    a16 = acc;
    #pragma unroll 4
    for (int s = 16; s < 32; ++s) { int mi = w + s; float v = (mi < TT) ? rnef(xb[mi]) : 0.f; acc = fmaf(v, v, acc); }
    a32 = acc;
    #pragma unroll 4
    for (int s = 32; s < 64; ++s) { int mi = w + s; float v = (mi < TT) ? rnef(xb[mi]) : 0.f; acc = fmaf(v, v, acc); }
    a64 = acc;
    float* x2 = (float*)(ws + OFF_X2);
    x2[(size_t)(0 * BB * CC + bc) * TT + w] = a16;
    x2[(size_t)(1 * BB * CC + bc) * TT + w] = a32;
    x2[(size_t)(2 * BB * CC + bc) * TT + w] = a64;
  }
}

// -- main: r16 exactly — best measured configuration (39.46 us) --
DEV void epi(const f32x16 a, const float* __restrict__ x2c, float s2c, int lhi, f32x16& dsum) {
  #pragma unroll
  for (int g = 0; g < 4; ++g) {
    const float4 xq = *(const float4*)(x2c + 4 * lhi + 8 * g);   // LDS broadcast, aligned
    #pragma unroll
    for (int j = 0; j < 4; ++j) {
      const int r2 = g * 4 + j;
      dsum[r2] += __builtin_amdgcn_sqrtf(fmaxf(fmaf(-2.f, a[r2], f4get(xq, j) + s2c), 1e-12f));
    }
  }
}

template<int S, int KST, int OUTOFF, size_t BOFF, int SIDX>
DEV void run(const unsigned char* __restrict__ ws, unsigned* __restrict__ outu,
             int r, float* __restrict__ x2l, float* __restrict__ s2l,
             float* __restrict__ mred)
{
  const int b = r >> 4, wg = r & 15;          // 16 w-groups of 128
  const int tid = (int)threadIdx.x;
  const int lane = tid & 63, wsub = tid >> 6;
  const int l31 = lane & 31, lhi = lane >> 5, p = l31 & 7;
  const int w0 = wg * 128 + wsub * 32;

  const uint4* Bg = (const uint4*)(ws + BOFF) + lane;

  // ---- issue first B group (kq=0,c=0) immediately (in flight through barrier) ----
  uint4 Bb[2][KST];
  #pragma unroll
  for (int kk = 0; kk < KST; ++kk) Bb[0][kk] = Bg[(size_t)kk * 64];

  // ---- hoist A-fragments (verified layout): reused across all 4 kq ----
  const unsigned short* XCb = (const unsigned short*)(ws + OFF_XC);
  uint4 A[CC][KST];
  #pragma unroll
  for (int c = 0; c < CC; ++c) {
    const unsigned short* xA = XCb + ((size_t)((b * CC + c) * 8) + p) * TP
                             + (w0 + 8 * (l31 >> 3) + 8 * lhi);
    #pragma unroll
    for (int kk = 0; kk < KST; ++kk) A[c][kk] = *(const uint4*)(xA + 16 * kk);
  }

  // ---- block stage: x2[3][128] (this w-group) + s2[3][128] (full K) ----
  const float* x2g = (const float*)(ws + OFF_X2) + (size_t)(SIDX * BB * CC + b * CC) * TT + wg * 128;
  const float* s2g = (const float*)(ws + OFF_S2) + SIDX * CC * KK;
  #pragma unroll
  for (int i0 = 0; i0 < 2; ++i0) {
    int i = i0 * 256 + tid;
    if (i < 384) {
      int c = i >> 7, q = i & 127;
      x2l[i] = x2g[(size_t)c * TT + q];
      s2l[i] = s2g[c * KK + q];
    }
  }
  __syncthreads();

  constexpr int W = TT - S + 1;
  float mq[4];

  #pragma unroll                              // FULL unroll (r8-proven)
  for (int kq = 0; kq < 4; ++kq) {
    f32x16 dsum{};
    #pragma unroll
    for (int c = 0; c < CC; ++c) {
      const int g  = kq * CC + c;             // flattened group id, literal after unroll
      const int pb = g & 1;
      if (g < 4 * CC - 1) {                   // prefetch next group's B while computing
        const int ng = g + 1;
        const int nkq = ng / CC, nc = ng - nkq * CC;
        #pragma unroll
        for (int kk = 0; kk < KST; ++kk)
          Bb[pb ^ 1][kk] = Bg[(size_t)(((nc * 4 + nkq) * KST + kk)) * 64];
      }
      f32x16 acc{};
      #pragma unroll
      for (int kk = 0; kk < KST; ++kk)
        acc = __builtin_amdgcn_mfma_f32_32x32x16_bf16(
            __builtin_bit_cast(bf16x8, A[c][kk]), __builtin_bit_cast(bf16x8, Bb[pb][kk]), acc, 0, 0, 0);
      const float s2c = s2l[c * 128 + kq * 32 + l31];
      epi(acc, x2l + c * 128 + wsub * 32, s2c, lhi, dsum);
    }
    // ---- per-kq min over rows + cross-half ----
    float m = __builtin_inff();
    if (w0 + 31 < W) {                        // wave-uniform fast path
      #pragma unroll
      for (int r2 = 0; r2 < 16; ++r2) m = fminf(m, dsum[r2]);
    } else {
      #pragma unroll
      for (int r2 = 0; r2 < 16; ++r2) {
        const int ro = (r2 & 3) + 8 * (r2 >> 2) + 4 * lhi;
        if (w0 + ro < W) m = fminf(m, dsum[r2]);
      }
    }
    mq[kq] = fminf(m, __shfl_xor(m, 32));
  }

  // ---- cross-wave LDS combine: 128 atomics/block instead of 512 ----
  if (lane < 32) {
    #pragma unroll
    for (int kq = 0; kq < 4; ++kq) mred[(wsub * 4 + kq) * 32 + l31] = mq[kq];
  }
  __syncthreads();
  if (tid < 128) {
    const int kq = tid >> 5, q = tid & 31;
    float v = fminf(fminf(mred[(0 * 4 + kq) * 32 + q], mred[(1 * 4 + kq) * 32 + q]),
                    fminf(mred[(2 * 4 + kq) * 32 + q], mred[(3 * 4 + kq) * 32 + q]));
    atomicMin(outu + (b * OUTK + OUTOFF + kq * 32 + q), __float_as_uint(v));
  }
}

__global__ __launch_bounds__(256, 3) void shapelets_main(
    const unsigned char* __restrict__ ws, unsigned* __restrict__ outu)
{
  __shared__ __attribute__((aligned(16))) float x2l[384];
  __shared__ __attribute__((aligned(16))) float s2l[384];
  __shared__ __attribute__((aligned(16))) float mred[512];
  // XCD-affinity decode (neutral, harmless): batch b -> XCD b&7; S64 first
  const int j    = (int)blockIdx.x;
  const int bl   = j & 7;
  const int midx = j >> 3;
  const int wg   = midx & 15;
  const int bh   = (midx >> 4) & 3;
  const int So   = midx >> 6;      // 0=S64 (first), 1=S32, 2=S16
  const int r    = (bh * 8 + bl) * 16 + wg;
  if (So == 0)      run<64, 4, 256, OFF_B64, 2>(ws, outu, r, x2l, s2l, mred);
  else if (So == 1) run<32, 2, 128, OFF_B32, 1>(ws, outu, r, x2l, s2l, mred);
  else              run<16, 1,   0, OFF_B16, 0>(ws, outu, r, x2l, s2l, mred);
}

} // namespace

extern "C" void kernel_launch(void* const* d_in, const int* in_sizes, int n_in,
                              void* d_out, int out_size, void* d_ws, size_t ws_size,
                              hipStream_t stream) {
  const float* x    = (const float*)d_in[0];
  const float* sh16 = (const float*)d_in[1];
  const float* sh32 = (const float*)d_in[2];
  const float* sh64 = (const float*)d_in[3];
  unsigned* outu = (unsigned*)d_out;
  unsigned char* ws = (unsigned char*)d_ws;

  precompute<<<(N_TOT + 255) / 256, 256, 0, stream>>>(x, sh16, sh32, sh64, ws, outu);
  shapelets_main<<<1536, 256, 0, stream>>>(ws, outu);
}